// Round 9
// baseline (924.281 us; speedup 1.0000x reference)
//
#include <hip/hip_runtime.h>
#include <hip/hip_bf16.h>
#include <math.h>

// ---------------- problem constants ----------------
#define BIMG   4
#define CIN    512
#define HF     50
#define WF     50
#define PIX    2500          // HF*WF
#define MTOT   10000         // BIMG*PIX
#define ANC    9
#define NLOC   22500         // PIX*ANC
#define NPRE   3000
#define NPOST  300
#define WORDS  47            // ceil(3000/64)
#define ROWPAD 3008
#define WSTRIDE 48           // padded words per NMS row
#define CAP    8192          // candidate capacity per image
#define KTOT   4608          // 9 taps * 512 channels
#define NSTEP  144           // KTOT / 32

// d_out layout (floats): rois, rois_idx, anchors, loc, bf_pred
#define ROIS_OFF 0
#define IDX_OFF  4800
#define ANC_OFF  6000
#define LOC_OFF  96000
#define BF_OFF   456000

#define RAWP_SZ   2560000UL                // 10000*64 f32

// ---- REG layout (proven 36,592,256-byte footprint) ----
#define WS_WPH   0UL
#define WS_WPL   4718592UL
#define WS_W1T   9437184UL
#define WS_PART  9568256UL
#define WS_SCORE 30048256UL
#define WS_BOXD  30768256UL
#define WS_SBD   33648256UL
#define WS_M     WS_PART
#define WS_CAND  (WS_PART + 4620288UL)
#define WS_CNT   (WS_CAND + 131072UL)
#define WS_RAWP3 34032256UL                // -> 36,592,256 total

// ---- GLOAD layouts (NHWC f16-split planes + global_load_lds staging) ----
#define G_WPH   0UL
#define G_WPL   4718592UL
#define G_W1T   9437184UL
#define G_INH   9568256UL                  // 10,240,000 (4*2500*512 f16)
#define G_INL   19808256UL                 // 10,240,000
#define G_PART  30048256UL                 // 1-pass: 20,480,000 ; 2-pass: 10,240,000
#define G1_NEED 50528256UL                 // PROVEN available (mode 1 ran in R5-R8)
// G1 overlays (after conv3x3): rawp in inh/inl region; small bufs in Wp region
#define G1_RAWP G_INH
#define G1_UKEY 0UL
#define G1_BOXD 720000UL
#define G1_SBD  3600000UL
#define G1_M    3984000UL
#define G1_CAND 8604288UL
#define G1_CNT  8735360UL
// G2 (two column passes of 256): rawp0/1 after partP (survive pass1), rawp2/3 in Wp region
#define G2_RAWP0 40288256UL
#define G2_RAWP1 42848256UL
#define G2_NEED  45408256UL
#define G2_RAWP2 0UL
#define G2_RAWP3 2560000UL
#define G2_UKEY  5120000UL
#define G2_BOXD  5840000UL
#define G2_SBD   8720000UL
#define G2_M     9104000UL
#define G2_CAND  13724288UL
#define G2_CNT   13855360UL

typedef _Float16 f16x8 __attribute__((ext_vector_type(8)));
typedef float f32x16 __attribute__((ext_vector_type(16)));

// Split f32 pair into (hi f16, lo f16*2^12) packed u32 planes: a ~= h + l*2^-12.
__device__ __forceinline__ void split_pair(float a, float b,
                                           unsigned& h, unsigned& l) {
  _Float16 ha = (_Float16)a, hb = (_Float16)b;
  float ra = (a - (float)ha) * 4096.0f;
  float rb = (b - (float)hb) * 4096.0f;
  _Float16 la = (_Float16)ra, lb = (_Float16)rb;
  unsigned short x0, x1, y0, y1;
  __builtin_memcpy(&x0, &ha, 2);
  __builtin_memcpy(&x1, &hb, 2);
  __builtin_memcpy(&y0, &la, 2);
  __builtin_memcpy(&y1, &lb, 2);
  h = (unsigned)x0 | ((unsigned)x1 << 16);
  l = (unsigned)y0 | ((unsigned)y1 << 16);
}

__device__ __forceinline__ void gload16(const void* g, void* l) {
  __builtin_amdgcn_global_load_lds(
      (const __attribute__((address_space(1))) unsigned int*)g,
      (__attribute__((address_space(3))) unsigned int*)l, 16, 0, 0);
}

// ---------------- kernel 0: weight prep (coalesced) ----------------
__global__ __launch_bounds__(256) void prep_kernel(
    const float* __restrict__ conv_w, const float* __restrict__ loc_w,
    const float* __restrict__ bf_w, unsigned* __restrict__ Wph,
    unsigned* __restrict__ Wpl, float* __restrict__ W1t) {
  int o = blockIdx.x * 256 + threadIdx.x;
  if (o < 512 * 256) {
    int co = o >> 8;
    int c2 = o & 255;
    const float* src = conv_w + ((size_t)co * 512 + 2 * c2) * 9;
    float w0[9], w1[9];
#pragma unroll
    for (int t = 0; t < 9; ++t) { w0[t] = src[t]; w1[t] = src[9 + t]; }
#pragma unroll
    for (int tap = 0; tap < 9; ++tap) {
      unsigned h, l;
      split_pair(w0[tap], w1[tap], h, l);
      size_t idx = (size_t)co * 2304 + tap * 256 + c2;
      Wph[idx] = h;
      Wpl[idx] = l;
    }
  } else {
    int o2 = o - 512 * 256;
    if (o2 < 512 * 64) {
      int co = o2 & 63;
      int c  = o2 >> 6;
      float v = 0.0f;
      if (co < 36)      v = loc_w[co * 512 + c];
      else if (co < 54) v = bf_w[(co - 36) * 512 + c];
      W1t[o2] = v;
    }
  }
}

// ---------------- kernel 0b: NCHW f32 -> NHWC f16-split planes ----------------
// R8-proven coalesced LDS-transpose version. Also zeroes the 2KB zero-page
// (zp = d_out rois region, rewritten later by nms_scan).
__global__ __launch_bounds__(256) void packin_kernel(
    const float* __restrict__ in, unsigned short* __restrict__ inh,
    unsigned short* __restrict__ inl, float* __restrict__ zp) {
  __shared__ float tl[64][65];
  if (blockIdx.x == 0 && blockIdx.y == 0 && blockIdx.z == 0) {
    zp[threadIdx.x] = 0.0f;
    zp[256 + threadIdx.x] = 0.0f;
  }
  const int bi = blockIdx.z;
  const int c0 = blockIdx.y * 64;
  const int p0 = blockIdx.x * 64;
  const int t = threadIdx.x;
  const int px = t & 63;
  const int wv = t >> 6;
  const float* src = in + (size_t)bi * CIN * PIX + (size_t)c0 * PIX + p0;
  const bool pv = (p0 + px) < PIX;
#pragma unroll
  for (int i = 0; i < 16; ++i) {
    int ch = wv + i * 4;
    tl[ch][px] = pv ? src[(size_t)ch * PIX + px] : 0.0f;
  }
  __syncthreads();
  const int oct = t & 7;
#pragma unroll
  for (int r = 0; r < 2; ++r) {
    int pxx = (t >> 3) + r * 32;
    int p = p0 + pxx;
    if (p < PIX) {
      unsigned hw[4], lw[4];
#pragma unroll
      for (int j = 0; j < 4; ++j) {
        float a  = tl[oct * 8 + 2 * j][pxx];
        float b2 = tl[oct * 8 + 2 * j + 1][pxx];
        split_pair(a, b2, hw[j], lw[j]);
      }
      size_t o = ((size_t)bi * PIX + p) * CIN + c0 + oct * 8;
      *(uint4*)&inh[o] = make_uint4(hw[0], hw[1], hw[2], hw[3]);
      *(uint4*)&inl[o] = make_uint4(lw[0], lw[1], lw[2], lw[3]);
    }
  }
}

// ---------------- conv3x3_reg LDS geometry (24KB buffers, unchanged) --------
#define LDS_A_H 0
#define LDS_A_L 8192
#define LDS_B_H 16384
#define LDS_B_L 20480
#define LDS_BUF 24576

// ---------------- kernel 1a: conv3x3, register-staged fallback (36.6MB ws) --
__global__ __launch_bounds__(512, 4) void conv3x3_reg(
    const float* __restrict__ in, const unsigned* __restrict__ Wph,
    const unsigned* __restrict__ Wpl, float* __restrict__ part0) {
  __shared__ __align__(16) unsigned char lds[2][LDS_BUF];
  const int tid = threadIdx.x;
  const int lane = tid & 63;
  const int w = tid >> 6;
  const int wr = w >> 1, wc = w & 1;
  const int il = lane & 31, g = lane >> 5;

  int flat = blockIdx.x;
  int sblk = (flat & 7) * 79 + (flat >> 3);
  const int mb = sblk >> 3, nb = sblk & 7;
  const int m0 = mb * 128, n0 = nb * 64;

  const int sr = tid & 127, o2 = tid >> 7;
  const int qa = m0 + sr;
  const bool qav = qa < MTOT;
  const int qq = qav ? qa : 0;
  const int bi = qq / PIX, rr = qq - bi * PIX;
  const int yy = rr / WF, xx = rr - yy * WF;
  const float* __restrict__ ibase = in + (size_t)bi * (CIN * PIX);
  const int bcol = tid & 63, boct = w & 3, bpl = w >> 2;
  const unsigned* __restrict__ wrow =
      (bpl ? Wpl : Wph) + (size_t)(n0 + bcol) * 2304 + boct * 4;

  f32x16 accm, accc;
#pragma unroll
  for (int r = 0; r < 16; ++r) { accm[r] = 0.f; accc[r] = 0.f; }

  float af[8];
  uint4 wq;

#define RFETCH(st_) {                                                          \
    int tap_ = (st_) >> 4;                                                     \
    int c0_ = ((st_) & 15) * 32;                                               \
    int dy_ = tap_ / 3 - 1, dx_ = tap_ % 3 - 1;                                \
    int iy_ = yy + dy_, ix_ = xx + dx_;                                        \
    bool ok_ = qav && ((unsigned)iy_ < (unsigned)HF) &&                        \
               ((unsigned)ix_ < (unsigned)WF);                                 \
    int off_ = iy_ * WF + ix_;                                                 \
    const float* ap_ = ibase + (size_t)(c0_ + o2 * 8) * PIX;                   \
    _Pragma("unroll") for (int j_ = 0; j_ < 8; ++j_)                           \
      af[j_] = ok_ ? ap_[off_ + j_ * PIX] : 0.0f;                              \
    wq = *(const uint4*)(wrow + (st_) * 16);                                   \
  }
#define RSTORE(buf_) {                                                         \
    unsigned h_[4], l_[4];                                                     \
    _Pragma("unroll") for (int t_ = 0; t_ < 4; ++t_)                           \
      split_pair(af[2 * t_], af[2 * t_ + 1], h_[t_], l_[t_]);                  \
    char* bp_ = (char*)&lds[buf_][0];                                          \
    *(uint4*)(bp_ + LDS_A_H + o2 * 2048 + sr * 16) =                           \
        make_uint4(h_[0], h_[1], h_[2], h_[3]);                                \
    *(uint4*)(bp_ + LDS_A_L + o2 * 2048 + sr * 16) =                           \
        make_uint4(l_[0], l_[1], l_[2], l_[3]);                                \
    *(uint4*)(bp_ + (bpl ? LDS_B_L : LDS_B_H) + boct * 1024 + bcol * 16) = wq; \
  }

  RFETCH(0);
  RSTORE(0);
  __syncthreads();

  int cur = 0;
#pragma unroll 1
  for (int st = 0; st < NSTEP; ++st) {
    const bool hn = (st + 1) < NSTEP;
    if (hn) RFETCH(st + 1);
    {
      const char* base_ = (const char*)&lds[cur][0];
#pragma unroll
      for (int h_ = 0; h_ < 2; ++h_) {
        const int oct_ = 2 * h_ + g;
        f16x8 ah_ = *(const f16x8*)(base_ + LDS_A_H + oct_ * 2048 +
                                    (wr * 32 + il) * 16);
        f16x8 al_ = *(const f16x8*)(base_ + LDS_A_L + oct_ * 2048 +
                                    (wr * 32 + il) * 16);
        f16x8 bh_ = *(const f16x8*)(base_ + LDS_B_H + oct_ * 1024 +
                                    (wc * 32 + il) * 16);
        f16x8 bl_ = *(const f16x8*)(base_ + LDS_B_L + oct_ * 1024 +
                                    (wc * 32 + il) * 16);
        accm = __builtin_amdgcn_mfma_f32_32x32x16_f16(ah_, bh_, accm, 0, 0, 0);
        accc = __builtin_amdgcn_mfma_f32_32x32x16_f16(ah_, bl_, accc, 0, 0, 0);
        accc = __builtin_amdgcn_mfma_f32_32x32x16_f16(al_, bh_, accc, 0, 0, 0);
      }
    }
    if (hn) RSTORE(cur ^ 1);
    __syncthreads();
    cur ^= 1;
  }
#undef RFETCH
#undef RSTORE

  const int colg = n0 + wc * 32 + il;
  const int rb0 = m0 + wr * 32 + 4 * g;
#pragma unroll
  for (int r = 0; r < 16; ++r) {
    int row = rb0 + (r & 3) + 8 * (r >> 2);
    if (row < MTOT)
      part0[(size_t)row * 512 + colg] =
          (float)((double)accm[r] + (double)accc[r] * (1.0 / 4096.0));
  }
}

// ---------------- kernel 1b: conv3x3 gload, 128x128 tile @ 16 waves/CU ------
// R9: block = 128(M) x 128(N), 512 threads = 8 waves of 32x64 tiles (4x2).
// Per wave per K32 step: 4 gloads (2 A + 2 B, shared addr math), 12
// ds_read_b128, 12 MFMAs (ratio 1.0). LDS buffer 32KB: A_h/A_l 8KB
// ([oct][128 rows][16B]) + B_h/B_l 8KB ([oct][128 cols][16B]) — K-major,
// conflict-free (R3/R5-R8 proven pattern). 2 buffers = 64KB -> 2 blocks/CU
// = 16 waves/CU (m97 occupancy regime: simple issue->compute->syncthreads,
// implicit wave overlap hides the barrier drain, m114). Halves total LDS
// traffic vs the 128x64 tile (5.8GB vs 8GB) -> floor ~84us.
#define GA_H 0
#define GA_L 8192
#define GB_H 16384
#define GB_L 24576
#define GBUF 32768

__global__ __launch_bounds__(512, 4) void conv3x3_g(
    const unsigned short* __restrict__ inh, const unsigned short* __restrict__ inl,
    const unsigned* __restrict__ Wph, const unsigned* __restrict__ Wpl,
    float* __restrict__ part0, const float* __restrict__ zp,
    int cbase, int lnb, int ldp) {
  __shared__ __align__(16) unsigned char lds[2][GBUF];
  const int tid = threadIdx.x;
  const int lane = tid & 63;
  const int w = tid >> 6;            // 0..7
  const int wr = w >> 1, wc2 = w & 1;
  const int il = lane & 31, g = lane >> 5;

  // bijective XCD-chunk swizzle (m204), nb-fast within XCD for A reuse
  int nwg = gridDim.x;
  int qd = nwg >> 3, rm = nwg & 7;
  int xcd = blockIdx.x & 7, bidx = blockIdx.x >> 3;
  int sblk = (xcd < rm ? xcd * (qd + 1) : rm * (qd + 1) + (xcd - rm) * qd) + bidx;
  const int mb = sblk >> lnb, nb = sblk & ((1 << lnb) - 1);
  const int mrow0 = mb * 128, n0 = nb * 128;
  const int n0g = cbase + n0;

  // staging roles: wave w stages A(oct=w&3, rh=w>>2) + B(oct=w&3, ch=w>>2)
  const int aoct = w & 3, arh = w >> 2;
  const int arow = mrow0 + arh * 64 + lane;
  const bool av = arow < MTOT;
  {
  }
  const int qq = av ? arow : 0;
  const int bi = qq / PIX;
  const int rrp = qq - bi * PIX;
  const int ya = rrp / WF, xa = rrp - ya * WF;
  const size_t biO = (size_t)bi * (PIX * CIN);
  const int boct = w & 3, bch = w >> 2;
  const int bcol = n0g + bch * 64 + lane;
  const unsigned* __restrict__ wbh = Wph + (size_t)bcol * 2304 + (boct << 2);
  const unsigned* __restrict__ wbl = Wpl + (size_t)bcol * 2304 + (boct << 2);

  f32x16 am0, am1, ac0, ac1;
#pragma unroll
  for (int r = 0; r < 16; ++r) { am0[r] = 0.f; am1[r] = 0.f; ac0[r] = 0.f; ac1[r] = 0.f; }

#define GISSUE(st_, bs_) {                                                     \
    int tap_ = (st_) >> 4;                                                     \
    int c0_ = ((st_) & 15) << 5;                                               \
    int t3_ = tap_ / 3;                                                        \
    int dy_ = t3_ - 1, dx_ = tap_ - 3 * t3_ - 1;                               \
    int iy_ = ya + dy_, ix_ = xa + dx_;                                        \
    bool ok_ = av && ((unsigned)iy_ < (unsigned)HF) &&                         \
               ((unsigned)ix_ < (unsigned)WF);                                 \
    size_t ae_ = biO + (size_t)(iy_ * WF + ix_) * CIN + c0_ + (aoct << 3);     \
    const void* sh_ = ok_ ? (const void*)(inh + ae_) : (const void*)zp;        \
    const void* sl_ = ok_ ? (const void*)(inl + ae_) : (const void*)zp;        \
    char* bp_ = (char*)&lds[bs_][0];                                           \
    gload16(sh_, bp_ + GA_H + aoct * 2048 + arh * 1024);                       \
    gload16(sl_, bp_ + GA_L + aoct * 2048 + arh * 1024);                       \
    gload16(wbh + (size_t)(st_) * 16, bp_ + GB_H + boct * 2048 + bch * 1024);  \
    gload16(wbl + (size_t)(st_) * 16, bp_ + GB_L + boct * 2048 + bch * 1024);  \
  }

#define GCOMPUTE(bs_) {                                                        \
    const char* base_ = (const char*)&lds[bs_][0];                             \
    _Pragma("unroll") for (int h_ = 0; h_ < 2; ++h_) {                         \
      const int oct_ = 2 * h_ + g;                                             \
      const char* pa_ = base_ + GA_H + oct_ * 2048 + (wr * 32 + il) * 16;      \
      const char* qa_ = base_ + GA_L + oct_ * 2048 + (wr * 32 + il) * 16;      \
      const char* pb_ = base_ + GB_H + oct_ * 2048 + (wc2 * 64 + il) * 16;     \
      const char* qb_ = base_ + GB_L + oct_ * 2048 + (wc2 * 64 + il) * 16;     \
      f16x8 ah_  = *(const f16x8*)(pa_);                                       \
      f16x8 al_  = *(const f16x8*)(qa_);                                       \
      f16x8 bh0_ = *(const f16x8*)(pb_);                                       \
      f16x8 bh1_ = *(const f16x8*)(pb_ + 512);                                 \
      f16x8 bl0_ = *(const f16x8*)(qb_);                                       \
      f16x8 bl1_ = *(const f16x8*)(qb_ + 512);                                 \
      am0 = __builtin_amdgcn_mfma_f32_32x32x16_f16(ah_, bh0_, am0, 0, 0, 0);   \
      am1 = __builtin_amdgcn_mfma_f32_32x32x16_f16(ah_, bh1_, am1, 0, 0, 0);   \
      ac0 = __builtin_amdgcn_mfma_f32_32x32x16_f16(ah_, bl0_, ac0, 0, 0, 0);   \
      ac0 = __builtin_amdgcn_mfma_f32_32x32x16_f16(al_, bh0_, ac0, 0, 0, 0);   \
      ac1 = __builtin_amdgcn_mfma_f32_32x32x16_f16(ah_, bl1_, ac1, 0, 0, 0);   \
      ac1 = __builtin_amdgcn_mfma_f32_32x32x16_f16(al_, bh1_, ac1, 0, 0, 0);   \
    }                                                                          \
  }

  GISSUE(0, 0);
  __syncthreads();   // compiler drains vmcnt -> buf0 landed

  int cur = 0;
#pragma unroll 1
  for (int st = 0; st < NSTEP; ++st) {
    if (st + 1 < NSTEP) GISSUE(st + 1, cur ^ 1);  // prefetch overlaps compute
    GCOMPUTE(cur);
    __syncthreads();                              // drain: next buffer landed
    cur ^= 1;
  }
#undef GISSUE
#undef GCOMPUTE

  // C/D 32x32 layout: col = lane&31, row = (r&3)+8*(r>>2)+4*(lane>>5)
  const int colp = n0 + wc2 * 64 + il;
  const int rb0 = mrow0 + wr * 32 + 4 * g;
#pragma unroll
  for (int r = 0; r < 16; ++r) {
    int row = rb0 + (r & 3) + 8 * (r >> 2);
    if (row < MTOT) {
      part0[(size_t)row * ldp + colp] =
          (float)((double)am0[r] + (double)ac0[r] * (1.0 / 4096.0));
      part0[(size_t)row * ldp + colp + 32] =
          (float)((double)am1[r] + (double)ac1[r] * (1.0 / 4096.0));
    }
  }
}

// ---------------- kernel 2: 1x1 heads, 64-pixel tile ----------------
__global__ __launch_bounds__(256) void conv1x1_kernel(
    const float* __restrict__ p0, int ldp, int cbase, int by0,
    const float* __restrict__ convb, const float* __restrict__ W1t,
    float* __restrict__ rawp0, float* __restrict__ rawp1,
    float* __restrict__ rawp2, float* __restrict__ rawp3) {
  __shared__ float As[16][64];
  const int tid = threadIdx.x;
  const int q0 = blockIdx.x * 64;
  const int by = by0 + blockIdx.y;
  const int lane = tid & 63;
  const int wv = tid >> 6;
  const int col0 = __builtin_amdgcn_readfirstlane(wv * 16);
  float* __restrict__ rp = (by == 0) ? rawp0 : (by == 1) ? rawp1 :
                           (by == 2) ? rawp2 : rawp3;

  const int sg = tid >> 6;
  const int sp = tid & 63;
  const int qs = q0 + sp;
  const bool okL = qs < MTOT;

  double acc[16];
  float accf[16];
#pragma unroll
  for (int c = 0; c < 16; ++c) { acc[c] = 0.0; accf[c] = 0.0f; }

  for (int kbl = 0; kbl < 8; ++kbl) {
    int kb = by * 8 + kbl;
    int c0 = kb * 16;                      // global channel
    float fv[4] = {0.0f, 0.0f, 0.0f, 0.0f};
    if (okL) {
      const size_t base = (size_t)qs * ldp + (c0 - cbase) + sg * 4;
      float4 a0 = *(const float4*)&p0[base];
      float4 bsv = *(const float4*)&convb[c0 + sg * 4];
      fv[0] = (float)fmax((double)a0.x + (double)bsv.x, 0.0);
      fv[1] = (float)fmax((double)a0.y + (double)bsv.y, 0.0);
      fv[2] = (float)fmax((double)a0.z + (double)bsv.z, 0.0);
      fv[3] = (float)fmax((double)a0.w + (double)bsv.w, 0.0);
    }
    __syncthreads();
#pragma unroll
    for (int j = 0; j < 4; ++j) As[sg * 4 + j][sp] = fv[j];
    __syncthreads();

    const float* __restrict__ Bw = W1t + (size_t)c0 * 64 + col0;
#pragma unroll
    for (int kk = 0; kk < 16; ++kk) {
      const float* __restrict__ br = Bw + (size_t)kk * 64;
      float a = As[kk][lane];
#pragma unroll
      for (int c = 0; c < 16; ++c)
        accf[c] = fmaf(a, br[c], accf[c]);   // br[c] wave-uniform -> scalar
    }
    if (kbl & 1) {
#pragma unroll
      for (int c = 0; c < 16; ++c) {
        acc[c] += (double)accf[c];
        accf[c] = 0.0f;
      }
    }
  }

  int q = q0 + lane;
  if (q < MTOT) {
    float o[16];
#pragma unroll
    for (int c = 0; c < 16; ++c) o[c] = (float)acc[c];
    float* fp = &rp[(size_t)q * 64 + col0];
#pragma unroll
    for (int g2 = 0; g2 < 4; ++g2)
      *(float4*)&fp[g2 * 4] = make_float4(o[g2*4], o[g2*4+1], o[g2*4+2], o[g2*4+3]);
  }
}

// ---------------- kernel 3: epilogue ----------------
__global__ __launch_bounds__(256) void epilogue_kernel(
    const float* __restrict__ r0, const float* __restrict__ r1,
    const float* __restrict__ r2, const float* __restrict__ r3,
    const float* __restrict__ locb, const float* __restrict__ bfb,
    float* __restrict__ d_out, double* __restrict__ boxd,
    unsigned long long* __restrict__ ukey,
    const int* __restrict__ imh, const int* __restrict__ imw) {
  int idx = blockIdx.x * 256 + threadIdx.x;
  if (idx >= BIMG * NLOC) return;
  int b = idx / NLOC;
  int i = idx - b * NLOC;
  int p = i / ANC;
  int a = i - p * ANC;
  int y = p / WF;
  int x = p - y * WF;
  int q = b * PIX + p;
  const size_t rb = (size_t)q * 64;

  float4 A0 = *(const float4*)&r0[rb + a * 4];
  float4 A1 = *(const float4*)&r1[rb + a * 4];
  float4 A2 = *(const float4*)&r2[rb + a * 4];
  float4 A3 = *(const float4*)&r3[rb + a * 4];
  double l0d = (((double)A0.x + (double)A1.x) + (double)A2.x) + (double)A3.x + (double)locb[a * 4 + 0];
  double l1d = (((double)A0.y + (double)A1.y) + (double)A2.y) + (double)A3.y + (double)locb[a * 4 + 1];
  double l2d = (((double)A0.z + (double)A1.z) + (double)A2.z) + (double)A3.z + (double)locb[a * 4 + 2];
  double l3d = (((double)A0.w + (double)A1.w) + (double)A2.w) + (double)A3.w + (double)locb[a * 4 + 3];
  *(float4*)&d_out[LOC_OFF + (size_t)idx * 4] =
      make_float4((float)l0d, (float)l1d, (float)l2d, (float)l3d);

  float2 G0 = *(const float2*)&r0[rb + 36 + a * 2];
  float2 G1 = *(const float2*)&r1[rb + 36 + a * 2];
  float2 G2 = *(const float2*)&r2[rb + 36 + a * 2];
  float2 G3 = *(const float2*)&r3[rb + 36 + a * 2];
  double g0 = (((double)G0.x + (double)G1.x) + (double)G2.x) + (double)G3.x + (double)bfb[a * 2 + 0];
  double g1 = (((double)G0.y + (double)G1.y) + (double)G2.y) + (double)G3.y + (double)bfb[a * 2 + 1];
  double m  = fmax(g0, g1);
  double e0 = exp(g0 - m), e1 = exp(g1 - m);
  double s  = e0 + e1;
  double p0 = e0 / s, p1 = e1 / s;
  *(float2*)&d_out[BF_OFF + (size_t)idx * 2] = make_float2((float)p0, (float)p1);

  int ridx = a / 3, sidx = a - ridx * 3;
  double ratio = (ridx == 0) ? 0.5 : ((ridx == 1) ? 1.0 : 2.0);
  double scale = (sidx == 0) ? 8.0 : ((sidx == 1) ? 16.0 : 32.0);
  double hs = 16.0 * scale * sqrt(ratio);
  double ws = 16.0 * scale * sqrt(1.0 / ratio);
  double sy = (double)(y * 16), sx = (double)(x * 16);
  double a0 = sy + (8.0 - hs * 0.5);
  double a1 = sx + (8.0 - ws * 0.5);
  double a2 = sy + (8.0 + hs * 0.5);
  double a3 = sx + (8.0 + ws * 0.5);
  if (b == 0) {
    *(float4*)&d_out[ANC_OFF + (size_t)i * 4] =
        make_float4((float)a0, (float)a1, (float)a2, (float)a3);
  }

  double ah = a2 - a0, aw = a3 - a1;
  double acy = a0 + 0.5 * ah, acx = a1 + 0.5 * aw;
  double cy = l0d * ah + acy;
  double cx = l1d * aw + acx;
  double hh = exp(l2d) * ah;
  double ww = exp(l3d) * aw;
  double ihf = (double)imh[0], iwf = (double)imw[0];
  double b0 = fmin(fmax(cy - 0.5 * hh, 0.0), ihf);
  double b1 = fmin(fmax(cx - 0.5 * ww, 0.0), iwf);
  double b2 = fmin(fmax(cy + 0.5 * hh, 0.0), ihf);
  double b3 = fmin(fmax(cx + 0.5 * ww, 0.0), iwf);
  double* bp = &boxd[(size_t)idx * 4];
  bp[0] = b0; bp[1] = b1; bp[2] = b2; bp[3] = b3;

  bool valid = (b2 - b0 >= 16.0) && (b3 - b1 >= 16.0);
  double d = valid ? (g1 - g0) : -INFINITY;
  long long bits = __double_as_longlong(d);
  unsigned long long u = (bits < 0)
      ? ~(unsigned long long)bits
      : ((unsigned long long)bits | 0x8000000000000000ull);
  ukey[idx] = ~u;
}

// ---------------- kernel 4a: histogram threshold + compaction ----------------
__global__ __launch_bounds__(1024) void thresh_kernel(
    const unsigned long long* __restrict__ ukey,
    unsigned* __restrict__ ccnt, unsigned* __restrict__ cand) {
  __shared__ unsigned hist[16384];
  __shared__ unsigned csum[1024];
  __shared__ unsigned sT, scnt;
  int b = blockIdx.x;
  int tid = threadIdx.x;
  for (int i = tid; i < 16384; i += 1024) hist[i] = 0;
  if (tid == 0) scnt = 0;
  __syncthreads();
  for (int j = tid; j < NLOC; j += 1024)
    atomicAdd(&hist[(unsigned)(ukey[(size_t)b * NLOC + j] >> 50)], 1u);
  __syncthreads();
  unsigned s = 0;
#pragma unroll
  for (int k = 0; k < 16; ++k) s += hist[tid * 16 + k];
  csum[tid] = s;
  __syncthreads();
  if (tid == 0) {
    unsigned cum = 0;
    int T = 16383;
    for (int c = 0; c < 1024; ++c) {
      if (cum + csum[c] >= NPRE) {
        unsigned cc = cum;
        for (int k = 0; k < 16; ++k) {
          cc += hist[c * 16 + k];
          if (cc >= NPRE) { T = c * 16 + k; break; }
        }
        break;
      }
      cum += csum[c];
    }
    sT = (unsigned)T;
  }
  __syncthreads();
  unsigned T = sT;
  for (int j = tid; j < NLOC; j += 1024) {
    if ((unsigned)(ukey[(size_t)b * NLOC + j] >> 50) <= T) {
      unsigned slot = atomicAdd(&scnt, 1u);
      if (slot < CAP) cand[(size_t)b * CAP + slot] = (unsigned)j;
    }
  }
  __syncthreads();
  if (tid == 0) ccnt[b] = scnt;
}

// ---------------- kernel 4b: exact rank among candidates -> sb ----------------
__global__ __launch_bounds__(256) void rank_kernel(
    const unsigned long long* __restrict__ ukey, const unsigned* __restrict__ ccnt,
    const unsigned* __restrict__ cand, const double* __restrict__ boxd,
    double* __restrict__ sbd) {
  __shared__ unsigned long long kt[256];
  __shared__ unsigned it[256];
  int b = blockIdx.y;
  int C = (int)min(ccnt[b], (unsigned)CAP);
  int s = blockIdx.x * 256 + threadIdx.x;
  bool act = s < C;
  unsigned myi = act ? cand[(size_t)b * CAP + s] : 0xFFFFFFFFu;
  unsigned long long ki = act ? ukey[(size_t)b * NLOC + myi] : ~0ull;
  int cnt = 0;
  int ntile = (C + 255) >> 8;
  for (int t = 0; t < ntile; ++t) {
    int j = t * 256 + threadIdx.x;
    unsigned ji = (j < C) ? cand[(size_t)b * CAP + j] : 0xFFFFFFFFu;
    kt[threadIdx.x] = (j < C) ? ukey[(size_t)b * NLOC + ji] : ~0ull;
    it[threadIdx.x] = ji;
    __syncthreads();
#pragma unroll 8
    for (int jj = 0; jj < 256; ++jj) {
      unsigned long long kj = kt[jj];
      unsigned jidx = it[jj];
      cnt += ((kj < ki) || (kj == ki && jidx < myi)) ? 1 : 0;
    }
    __syncthreads();
  }
  if (act && cnt < NPRE) {
    const double* bx = &boxd[((size_t)b * NLOC + myi) * 4];
    double* dp = &sbd[((size_t)b * NPRE + cnt) * 4];
    dp[0] = bx[0]; dp[1] = bx[1]; dp[2] = bx[2]; dp[3] = bx[3];
  }
}

// ---------------- kernel 5: NMS bitmask matrix (f64, div-free IoU) ----------------
__global__ __launch_bounds__(64) void nmsmask_kernel(
    const double* __restrict__ sbd, unsigned long long* __restrict__ M) {
  __shared__ double cb[64][4];
  __shared__ double ca[64];
  int b = blockIdx.z;
  int jw = blockIdx.y;
  int i  = blockIdx.x * 64 + threadIdx.x;
  int j  = jw * 64 + threadIdx.x;
  double j0 = 0, j1 = 0, j2 = 0, j3 = 0;
  if (j < NPRE) {
    const double* bp = &sbd[((size_t)b * NPRE + j) * 4];
    j0 = bp[0]; j1 = bp[1]; j2 = bp[2]; j3 = bp[3];
  }
  cb[threadIdx.x][0] = j0; cb[threadIdx.x][1] = j1;
  cb[threadIdx.x][2] = j2; cb[threadIdx.x][3] = j3;
  ca[threadIdx.x] = (j2 - j0) * (j3 - j1) + 1e-9;
  __syncthreads();
  if (i >= NPRE) return;
  const double* bp = &sbd[((size_t)b * NPRE + i) * 4];
  double i0 = bp[0], i1 = bp[1], i2 = bp[2], i3 = bp[3];
  double ai = (i2 - i0) * (i3 - i1);
  unsigned long long mask = 0ull;
#pragma unroll 4
  for (int t = 0; t < 64; ++t) {
    double h = fmax(fmin(i2, cb[t][2]) - fmax(i0, cb[t][0]), 0.0);
    double w = fmax(fmin(i3, cb[t][3]) - fmax(i1, cb[t][1]), 0.0);
    double inter = h * w;
    double rhs = 0.7 * (ai + ca[t] - inter);
    mask |= ((inter > rhs) ? 1ull : 0ull) << t;
  }
  M[((size_t)b * ROWPAD + i) * WSTRIDE + jw] = mask;
}

// ---------------- kernel 6: windowed sequential NMS scan (R8-proven) --------
#define RSTR 49
__global__ __launch_bounds__(64) void nms_scan_kernel(
    const double* __restrict__ sbd, const unsigned long long* __restrict__ M,
    float* __restrict__ d_out) {
  __shared__ unsigned long long rows[64][RSTR];   // 25,088 B
  int b = blockIdx.x;
  int lane = threadIdx.x;
  for (int k = lane; k < NPOST; k += 64) {
    *(float4*)&d_out[ROIS_OFF + (size_t)(b * NPOST + k) * 4] = make_float4(0, 0, 0, 0);
    d_out[IDX_OFF + b * NPOST + k] = (float)b;
  }

  unsigned long long R = ~0ull;
  if (lane < WORDS) R = 0ull;
  for (int w = 0; w < WORDS; ++w) {
    int j = w * 64 + lane;
    bool inval = true;
    if (j < NPRE) {
      const double* bp = &sbd[((size_t)b * NPRE + j) * 4];
      double h = bp[2] - bp[0], wd = bp[3] - bp[1];
      inval = !(h >= 16.0 && wd >= 16.0);
    }
    unsigned long long bal = __ballot(inval ? 1 : 0);
    if (lane == w) R |= bal;
  }

  int kept = 0;
  for (int w0 = 0; w0 < WORDS && kept < NPOST; ++w0) {
    int j = w0 * 64 + lane;
    __syncthreads();                 // previous window's LDS reads done
    if (j < NPRE) {
      const unsigned long long* mr = &M[((size_t)b * ROWPAD + j) * WSTRIDE];
#pragma unroll
      for (int k = 0; k < WORDS; ++k) rows[lane][k] = mr[k];
    }
    __syncthreads();
    unsigned long long word = __shfl(R, w0);   // suppression bits, window w0
    while (kept < NPOST) {
      unsigned long long avail = ~word;
      if (avail == 0ull) break;
      int bit = __ffsll(avail) - 1;
      int i = w0 * 64 + bit;
      if (lane < 4)
        d_out[ROIS_OFF + (size_t)(b * NPOST + kept) * 4 + lane] =
            (float)sbd[((size_t)b * NPRE + i) * 4 + lane];
      kept++;
      if (kept >= NPOST) break;
      unsigned long long rw = (lane < WORDS) ? rows[bit][lane] : 0ull;
      R |= rw;
      word |= (1ull << bit);
      word |= __shfl(rw, w0);
    }
  }
}

// ---------------- launch ----------------
extern "C" void kernel_launch(void* const* d_in, const int* in_sizes, int n_in,
                              void* d_out, int out_size, void* d_ws, size_t ws_size,
                              hipStream_t stream) {
  const float* in     = (const float*)d_in[0];
  const float* conv_w = (const float*)d_in[1];
  const float* conv_b = (const float*)d_in[2];
  const float* bf_w   = (const float*)d_in[3];
  const float* bf_b   = (const float*)d_in[4];
  const float* loc_w  = (const float*)d_in[5];
  const float* loc_b  = (const float*)d_in[6];
  const int*   imh    = (const int*)d_in[7];
  const int*   imw    = (const int*)d_in[8];
  float* out = (float*)d_out;
  char* ws = (char*)d_ws;

  // mode: 1 = gload 1-pass (PROVEN active in R5-R8), 2 = gload 2-pass, 0 = reg
  const int mode = (ws_size >= G1_NEED) ? 1 : (ws_size >= G2_NEED) ? 2 : 0;

  if (mode == 0) {
    unsigned* Wph  = (unsigned*)(ws + WS_WPH);
    unsigned* Wpl  = (unsigned*)(ws + WS_WPL);
    float*    W1t  = (float*)(ws + WS_W1T);
    float*    part0 = (float*)(ws + WS_PART);
    unsigned long long* ukey = (unsigned long long*)(ws + WS_SCORE);
    double*   boxd = (double*)(ws + WS_BOXD);
    double*   sbd  = (double*)(ws + WS_SBD);
    unsigned long long* M = (unsigned long long*)(ws + WS_M);
    unsigned* cand = (unsigned*)(ws + WS_CAND);
    unsigned* ccnt = (unsigned*)(ws + WS_CNT);
    float* rawp0 = (float*)(ws + WS_WPH);
    float* rawp1 = (float*)(ws + WS_WPH + RAWP_SZ);
    float* rawp2 = (float*)(ws + WS_WPH + 2 * RAWP_SZ);
    float* rawp3 = (float*)(ws + WS_RAWP3);

    hipLaunchKernelGGL(prep_kernel, dim3((512 * 256 + 512 * 64 + 255) / 256),
                       dim3(256), 0, stream, conv_w, loc_w, bf_w, Wph, Wpl, W1t);
    hipLaunchKernelGGL(conv3x3_reg, dim3(632), dim3(512), 0, stream,
                       in, (const unsigned*)Wph, (const unsigned*)Wpl, part0);
    hipLaunchKernelGGL(conv1x1_kernel, dim3(157, 4), dim3(256), 0, stream,
                       part0, 512, 0, 0, conv_b, W1t, rawp0, rawp1, rawp2, rawp3);
    hipLaunchKernelGGL(epilogue_kernel, dim3((BIMG * NLOC + 255) / 256), dim3(256),
                       0, stream, rawp0, rawp1, rawp2, rawp3, loc_b, bf_b, out,
                       boxd, ukey, imh, imw);
    hipLaunchKernelGGL(thresh_kernel, dim3(4), dim3(1024), 0, stream, ukey, ccnt, cand);
    hipLaunchKernelGGL(rank_kernel, dim3(CAP / 256, 4), dim3(256), 0, stream,
                       ukey, ccnt, cand, boxd, sbd);
    hipLaunchKernelGGL(nmsmask_kernel, dim3(47, 47, 4), dim3(64), 0, stream, sbd, M);
    hipLaunchKernelGGL(nms_scan_kernel, dim3(4), dim3(64), 0, stream, sbd, M, out);
    return;
  }

  unsigned* Wph = (unsigned*)(ws + G_WPH);
  unsigned* Wpl = (unsigned*)(ws + G_WPL);
  float*    W1t = (float*)(ws + G_W1T);
  unsigned short* inh = (unsigned short*)(ws + G_INH);
  unsigned short* inl = (unsigned short*)(ws + G_INL);
  float* partP = (float*)(ws + G_PART);

  hipLaunchKernelGGL(prep_kernel, dim3((512 * 256 + 512 * 64 + 255) / 256),
                     dim3(256), 0, stream, conv_w, loc_w, bf_w, Wph, Wpl, W1t);
  hipLaunchKernelGGL(packin_kernel, dim3(40, 8, BIMG), dim3(256), 0, stream,
                     in, inh, inl, out);

  float *rawp0, *rawp1, *rawp2, *rawp3;
  unsigned long long *ukey, *M;
  double *boxd, *sbd;
  unsigned *cand, *ccnt;

  if (mode == 1) {
    rawp0 = (float*)(ws + G1_RAWP);
    rawp1 = (float*)(ws + G1_RAWP + RAWP_SZ);
    rawp2 = (float*)(ws + G1_RAWP + 2 * RAWP_SZ);
    rawp3 = (float*)(ws + G1_RAWP + 3 * RAWP_SZ);
    ukey = (unsigned long long*)(ws + G1_UKEY);
    boxd = (double*)(ws + G1_BOXD);
    sbd  = (double*)(ws + G1_SBD);
    M    = (unsigned long long*)(ws + G1_M);
    cand = (unsigned*)(ws + G1_CAND);
    ccnt = (unsigned*)(ws + G1_CNT);

    // 316 = 79 mb x 4 nb (128-col tiles)
    hipLaunchKernelGGL(conv3x3_g, dim3(316), dim3(512), 0, stream,
                       inh, inl, (const unsigned*)Wph, (const unsigned*)Wpl,
                       partP, (const float*)out, 0, 2, 512);
    hipLaunchKernelGGL(conv1x1_kernel, dim3(157, 4), dim3(256), 0, stream,
                       partP, 512, 0, 0, conv_b, W1t, rawp0, rawp1, rawp2, rawp3);
  } else {
    rawp0 = (float*)(ws + G2_RAWP0);
    rawp1 = (float*)(ws + G2_RAWP1);
    rawp2 = (float*)(ws + G2_RAWP2);
    rawp3 = (float*)(ws + G2_RAWP3);
    ukey = (unsigned long long*)(ws + G2_UKEY);
    boxd = (double*)(ws + G2_BOXD);
    sbd  = (double*)(ws + G2_SBD);
    M    = (unsigned long long*)(ws + G2_M);
    cand = (unsigned*)(ws + G2_CAND);
    ccnt = (unsigned*)(ws + G2_CNT);

    // 158 = 79 mb x 2 nb per 256-col pass
    hipLaunchKernelGGL(conv3x3_g, dim3(158), dim3(512), 0, stream,
                       inh, inl, (const unsigned*)Wph, (const unsigned*)Wpl,
                       partP, (const float*)out, 0, 1, 256);
    hipLaunchKernelGGL(conv1x1_kernel, dim3(157, 2), dim3(256), 0, stream,
                       partP, 256, 0, 0, conv_b, W1t, rawp0, rawp1, rawp2, rawp3);
    hipLaunchKernelGGL(conv3x3_g, dim3(158), dim3(512), 0, stream,
                       inh, inl, (const unsigned*)Wph, (const unsigned*)Wpl,
                       partP, (const float*)out, 256, 1, 256);
    hipLaunchKernelGGL(conv1x1_kernel, dim3(157, 2), dim3(256), 0, stream,
                       partP, 256, 256, 2, conv_b, W1t, rawp0, rawp1, rawp2, rawp3);
  }

  hipLaunchKernelGGL(epilogue_kernel, dim3((BIMG * NLOC + 255) / 256), dim3(256),
                     0, stream, rawp0, rawp1, rawp2, rawp3, loc_b, bf_b, out,
                     boxd, ukey, imh, imw);
  hipLaunchKernelGGL(thresh_kernel, dim3(4), dim3(1024), 0, stream, ukey, ccnt, cand);
  hipLaunchKernelGGL(rank_kernel, dim3(CAP / 256, 4), dim3(256), 0, stream,
                     ukey, ccnt, cand, boxd, sbd);
  hipLaunchKernelGGL(nmsmask_kernel, dim3(47, 47, 4), dim3(64), 0, stream, sbd, M);
  hipLaunchKernelGGL(nms_scan_kernel, dim3(4), dim3(64), 0, stream, sbd, M, out);
}

// Round 11
// 795.961 us; speedup vs baseline: 1.1612x; 1.1612x over previous
//
#include <hip/hip_runtime.h>
#include <hip/hip_bf16.h>
#include <math.h>

// ---------------- problem constants ----------------
#define BIMG   4
#define CIN    512
#define HF     50
#define WF     50
#define PIX    2500          // HF*WF
#define MTOT   10000         // BIMG*PIX
#define ANC    9
#define NLOC   22500         // PIX*ANC
#define NPRE   3000
#define NPOST  300
#define WORDS  47            // ceil(3000/64)
#define ROWPAD 3008
#define WSTRIDE 48           // padded words per NMS row
#define CAP    8192          // candidate capacity per image
#define KTOT   4608          // 9 taps * 512 channels
#define NSTEP  144           // KTOT / 32

// d_out layout (floats): rois, rois_idx, anchors, loc, bf_pred
#define ROIS_OFF 0
#define IDX_OFF  4800
#define ANC_OFF  6000
#define LOC_OFF  96000
#define BF_OFF   456000

#define RAWP_SZ   2560000UL                // 10000*64 f32

// ---- REG layout (proven 36,592,256-byte footprint) ----
#define WS_WPH   0UL
#define WS_WPL   4718592UL
#define WS_W1T   9437184UL
#define WS_PART  9568256UL
#define WS_SCORE 30048256UL
#define WS_BOXD  30768256UL
#define WS_SBD   33648256UL
#define WS_M     WS_PART
#define WS_CAND  (WS_PART + 4620288UL)
#define WS_CNT   (WS_CAND + 131072UL)
#define WS_RAWP3 34032256UL                // -> 36,592,256 total

// ---- GLOAD layouts (k-octet-major f16-split planes, contiguous gloads) ----
#define G_WPH   0UL
#define G_WPL   4718592UL
#define G_W1T   9437184UL
#define G_INH   9568256UL                  // 10,240,000 (64 oct x 10000 px x 16B)
#define G_INL   19808256UL                 // 10,240,000
#define G_PART  30048256UL                 // 1-pass: 20,480,000 ; 2-pass: 10,240,000
#define G1_NEED 50528256UL                 // PROVEN available (mode 1 ran in R5-R10)
// G1 overlays (after conv3x3): rawp in inh/inl region; small bufs in Wp region
#define G1_RAWP G_INH
#define G1_UKEY 0UL
#define G1_BOXD 720000UL
#define G1_SBD  3600000UL
#define G1_M    3984000UL
#define G1_CAND 8604288UL
#define G1_CNT  8735360UL
// G2 (two column passes of 256): rawp0/1 after partP (survive pass1), rawp2/3 in Wp region
#define G2_RAWP0 40288256UL
#define G2_RAWP1 42848256UL
#define G2_NEED  45408256UL
#define G2_RAWP2 0UL
#define G2_RAWP3 2560000UL
#define G2_UKEY  5120000UL
#define G2_BOXD  5840000UL
#define G2_SBD   8720000UL
#define G2_M     9104000UL
#define G2_CAND  13724288UL
#define G2_CNT   13855360UL

typedef _Float16 f16x8 __attribute__((ext_vector_type(8)));
typedef float f32x16 __attribute__((ext_vector_type(16)));

// Split f32 pair into (hi f16, lo f16*2^12) packed u32 planes: a ~= h + l*2^-12.
__device__ __forceinline__ void split_pair(float a, float b,
                                           unsigned& h, unsigned& l) {
  _Float16 ha = (_Float16)a, hb = (_Float16)b;
  float ra = (a - (float)ha) * 4096.0f;
  float rb = (b - (float)hb) * 4096.0f;
  _Float16 la = (_Float16)ra, lb = (_Float16)rb;
  unsigned short x0, x1, y0, y1;
  __builtin_memcpy(&x0, &ha, 2);
  __builtin_memcpy(&x1, &hb, 2);
  __builtin_memcpy(&y0, &la, 2);
  __builtin_memcpy(&y1, &lb, 2);
  h = (unsigned)x0 | ((unsigned)x1 << 16);
  l = (unsigned)y0 | ((unsigned)y1 << 16);
}

__device__ __forceinline__ void gload16(const void* g, void* l) {
  __builtin_amdgcn_global_load_lds(
      (const __attribute__((address_space(1))) unsigned int*)g,
      (__attribute__((address_space(3))) unsigned int*)l, 16, 0, 0);
}

// ---------------- kernel 0: weight prep ----------------
// W layout (contiguous gloads): cell K*512 + col, K = tap*64 + oct
// (K-octet 0..575), cell = 16B = 4 u32 = channels 8oct..8oct+7 of col.
// Wave B-load: lane = col -> base + lane*16 = contiguous 1KB burst.
__global__ __launch_bounds__(256) void prep_kernel(
    const float* __restrict__ conv_w, const float* __restrict__ loc_w,
    const float* __restrict__ bf_w, unsigned* __restrict__ Wph,
    unsigned* __restrict__ Wpl, float* __restrict__ W1t) {
  int o = blockIdx.x * 256 + threadIdx.x;
  if (o < 512 * 256) {
    int co = o >> 8;          // output col
    int c2 = o & 255;         // channel pair (2c2, 2c2+1)
    const float* src = conv_w + ((size_t)co * 512 + 2 * c2) * 9;
    float w0[9], w1[9];
#pragma unroll
    for (int t = 0; t < 9; ++t) { w0[t] = src[t]; w1[t] = src[9 + t]; }
    int octk = c2 >> 2;       // channel oct within tap (0..63)
    int slot = c2 & 3;        // u32 slot within 16B cell
#pragma unroll
    for (int tap = 0; tap < 9; ++tap) {
      unsigned h, l;
      split_pair(w0[tap], w1[tap], h, l);
      size_t idx = ((size_t)(tap * 64 + octk) * 512 + co) * 4 + slot;
      Wph[idx] = h;
      Wpl[idx] = l;
    }
  } else {
    int o2 = o - 512 * 256;
    if (o2 < 512 * 64) {
      int co = o2 & 63;
      int c  = o2 >> 6;
      float v = 0.0f;
      if (co < 36)      v = loc_w[co * 512 + c];
      else if (co < 54) v = bf_w[(co - 36) * 512 + c];
      W1t[o2] = v;
    }
  }
}

// ---------------- kernel 0b: NCHW f32 -> channel-octet-major f16-split planes
// A layout: cell O*MTOT + q (O = CHANNEL octet 0..63, q = global pixel),
// cell = 16B = 8 f16. Wave A-load of 64 consecutive rows -> contiguous 1KB.
// Coalesced read via LDS transpose (R8-proven). Also zeroes the 2KB zero-page
// (zp = d_out rois region, rewritten later by nms_scan).
__global__ __launch_bounds__(256) void packin_kernel(
    const float* __restrict__ in, unsigned short* __restrict__ inh,
    unsigned short* __restrict__ inl, float* __restrict__ zp) {
  __shared__ float tl[64][65];
  if (blockIdx.x == 0 && blockIdx.y == 0 && blockIdx.z == 0) {
    zp[threadIdx.x] = 0.0f;
    zp[256 + threadIdx.x] = 0.0f;
  }
  const int bi = blockIdx.z;
  const int c0 = blockIdx.y * 64;
  const int p0 = blockIdx.x * 64;
  const int t = threadIdx.x;
  const int px = t & 63;
  const int wv = t >> 6;
  const float* src = in + (size_t)bi * CIN * PIX + (size_t)c0 * PIX + p0;
  const bool pv = (p0 + px) < PIX;
#pragma unroll
  for (int i = 0; i < 16; ++i) {
    int ch = wv + i * 4;
    tl[ch][px] = pv ? src[(size_t)ch * PIX + px] : 0.0f;
  }
  __syncthreads();
  const int o8 = t >> 5;          // oct within this 64-ch block (0..7)
  const int l32 = t & 31;
#pragma unroll
  for (int r = 0; r < 2; ++r) {
    int pxx = l32 + r * 32;
    int p = p0 + pxx;
    if (p < PIX) {
      unsigned hw[4], lw[4];
#pragma unroll
      for (int j = 0; j < 4; ++j) {
        float a  = tl[o8 * 8 + 2 * j][pxx];
        float b2 = tl[o8 * 8 + 2 * j + 1][pxx];
        split_pair(a, b2, hw[j], lw[j]);
      }
      int O = (c0 >> 3) + o8;     // global channel oct (0..63)
      size_t oo = ((size_t)O * MTOT + (size_t)bi * PIX + p) * 8;
      *(uint4*)&inh[oo] = make_uint4(hw[0], hw[1], hw[2], hw[3]);
      *(uint4*)&inl[oo] = make_uint4(lw[0], lw[1], lw[2], lw[3]);
    }
  }
}

// ---------------- conv3x3 shared LDS geometry ----------------
// K-major planes (R3/R5-R9-proven conflict-free): A[oct][128 rows][16B] (8KB),
// B[oct][64 cols][16B] (4KB); h+l planes -> 24KB per K32 buffer.
#define LDS_A_H 0
#define LDS_A_L 8192
#define LDS_B_H 16384
#define LDS_B_L 20480
#define LDS_BUF 24576

// ---------------- kernel 1a: conv3x3, register-staged fallback (36.6MB ws) --
__global__ __launch_bounds__(512, 4) void conv3x3_reg(
    const float* __restrict__ in, const unsigned* __restrict__ Wph,
    const unsigned* __restrict__ Wpl, float* __restrict__ part0) {
  __shared__ __align__(16) unsigned char lds[2][LDS_BUF];
  const int tid = threadIdx.x;
  const int lane = tid & 63;
  const int w = tid >> 6;
  const int wr = w >> 1, wc = w & 1;
  const int il = lane & 31, g = lane >> 5;

  int flat = blockIdx.x;
  int sblk = (flat & 7) * 79 + (flat >> 3);
  const int mb = sblk >> 3, nb = sblk & 7;
  const int m0 = mb * 128, n0 = nb * 64;

  const int sr = tid & 127, o2 = tid >> 7;
  const int qa = m0 + sr;
  const bool qav = qa < MTOT;
  const int qq = qav ? qa : 0;
  const int bi = qq / PIX, rr = qq - bi * PIX;
  const int yy = rr / WF, xx = rr - yy * WF;
  const float* __restrict__ ibase = in + (size_t)bi * (CIN * PIX);
  const int bcol = tid & 63, boct = w & 3, bpl = w >> 2;
  // W layout: cell (4*st + boct)*512 + n0 + bcol, advance 8192 u32/step
  const unsigned* __restrict__ wrow =
      (bpl ? Wpl : Wph) + ((size_t)boct * 512 + n0 + bcol) * 4;

  f32x16 accm, accc;
#pragma unroll
  for (int r = 0; r < 16; ++r) { accm[r] = 0.f; accc[r] = 0.f; }

  float af[8];
  uint4 wq;

#define RFETCH(st_) {                                                          \
    int tap_ = (st_) >> 4;                                                     \
    int c0_ = ((st_) & 15) * 32;                                               \
    int dy_ = tap_ / 3 - 1, dx_ = tap_ % 3 - 1;                                \
    int iy_ = yy + dy_, ix_ = xx + dx_;                                        \
    bool ok_ = qav && ((unsigned)iy_ < (unsigned)HF) &&                        \
               ((unsigned)ix_ < (unsigned)WF);                                 \
    int off_ = iy_ * WF + ix_;                                                 \
    const float* ap_ = ibase + (size_t)(c0_ + o2 * 8) * PIX;                   \
    _Pragma("unroll") for (int j_ = 0; j_ < 8; ++j_)                           \
      af[j_] = ok_ ? ap_[off_ + j_ * PIX] : 0.0f;                              \
    wq = *(const uint4*)(wrow + (size_t)(st_) * 8192);                         \
  }
#define RSTORE(buf_) {                                                         \
    unsigned h_[4], l_[4];                                                     \
    _Pragma("unroll") for (int t_ = 0; t_ < 4; ++t_)                           \
      split_pair(af[2 * t_], af[2 * t_ + 1], h_[t_], l_[t_]);                  \
    char* bp_ = (char*)&lds[buf_][0];                                          \
    *(uint4*)(bp_ + LDS_A_H + o2 * 2048 + sr * 16) =                           \
        make_uint4(h_[0], h_[1], h_[2], h_[3]);                                \
    *(uint4*)(bp_ + LDS_A_L + o2 * 2048 + sr * 16) =                           \
        make_uint4(l_[0], l_[1], l_[2], l_[3]);                                \
    *(uint4*)(bp_ + (bpl ? LDS_B_L : LDS_B_H) + boct * 1024 + bcol * 16) = wq; \
  }

  RFETCH(0);
  RSTORE(0);
  __syncthreads();

  int cur = 0;
#pragma unroll 1
  for (int st = 0; st < NSTEP; ++st) {
    const bool hn = (st + 1) < NSTEP;
    if (hn) RFETCH(st + 1);
    {
      const char* base_ = (const char*)&lds[cur][0];
#pragma unroll
      for (int h_ = 0; h_ < 2; ++h_) {
        const int oct_ = 2 * h_ + g;
        f16x8 ah_ = *(const f16x8*)(base_ + LDS_A_H + oct_ * 2048 +
                                    (wr * 32 + il) * 16);
        f16x8 al_ = *(const f16x8*)(base_ + LDS_A_L + oct_ * 2048 +
                                    (wr * 32 + il) * 16);
        f16x8 bh_ = *(const f16x8*)(base_ + LDS_B_H + oct_ * 1024 +
                                    (wc * 32 + il) * 16);
        f16x8 bl_ = *(const f16x8*)(base_ + LDS_B_L + oct_ * 1024 +
                                    (wc * 32 + il) * 16);
        accm = __builtin_amdgcn_mfma_f32_32x32x16_f16(ah_, bh_, accm, 0, 0, 0);
        accc = __builtin_amdgcn_mfma_f32_32x32x16_f16(ah_, bl_, accc, 0, 0, 0);
        accc = __builtin_amdgcn_mfma_f32_32x32x16_f16(al_, bh_, accc, 0, 0, 0);
      }
    }
    if (hn) RSTORE(cur ^ 1);
    __syncthreads();
    cur ^= 1;
  }
#undef RFETCH
#undef RSTORE

  const int colg = n0 + wc * 32 + il;
  const int rb0 = m0 + wr * 32 + 4 * g;
#pragma unroll
  for (int r = 0; r < 16; ++r) {
    int row = rb0 + (r & 3) + 8 * (r >> 2);
    if (row < MTOT)
      part0[(size_t)row * 512 + colg] =
          (float)((double)accm[r] + (double)accc[r] * (1.0 / 4096.0));
  }
}

// ---------------- kernel 1b: conv3x3 gload, 3-buf counted-vmcnt, CONTIGUOUS -
// R6-measured-best schedule verbatim; gload ADDRESSES use the octet-major
// layouts so every A/B gload is base + lane*16 contiguous (1KB burst).
// R10 BUG FIX: A is indexed by CHANNEL octet ((st&15)*4 + w, range 0..63) —
// the tap enters A only via the pixel shift. B is indexed by K-octet
// (4*st + w = tap*64 + choct, range 0..575). R10 used 4*st+w for BOTH,
// reading ~80MB past inh for taps>=1 -> absmax 748.
__global__ __launch_bounds__(256, 2) void conv3x3_g(
    const unsigned short* __restrict__ inh, const unsigned short* __restrict__ inl,
    const unsigned* __restrict__ Wph, const unsigned* __restrict__ Wpl,
    float* __restrict__ part0, const float* __restrict__ zp,
    int cbase, int lnb, int ldp) {
  __shared__ __align__(16) unsigned char lds[3][LDS_BUF];
  const int tid = threadIdx.x;
  const int lane = tid & 63;
  const int w = tid >> 6;
  const int wr = w >> 1, wc = w & 1;
  const int il = lane & 31, g = lane >> 5;

  // bijective XCD-chunk swizzle (m204), nb-fast within XCD for A reuse
  int nwg = gridDim.x;
  int qd = nwg >> 3, rm = nwg & 7;
  int xcd = blockIdx.x & 7, bidx = blockIdx.x >> 3;
  int sblk = (xcd < rm ? xcd * (qd + 1) : rm * (qd + 1) + (xcd - rm) * qd) + bidx;
  const int mb = sblk >> lnb, nb = sblk & ((1 << lnb) - 1);
  const int mrow0 = mb * 128, n0 = nb * 64;
  const int n0g = cbase + n0;

  // A geometry for the two 64-row halves this wave stages
  int arw[2], ya[2], xa[2];
  bool va[2];
#pragma unroll
  for (int rh = 0; rh < 2; ++rh) {
    int q = mrow0 + rh * 64 + lane;
    bool v = q < MTOT;
    int qq = v ? q : 0;
    int bi = qq / PIX, rrp = qq - bi * PIX;
    ya[rh] = rrp / WF;
    xa[rh] = rrp - ya[rh] * WF;
    arw[rh] = qq;
    va[rh] = v;
  }

  f32x16 am0, am1, ac0, ac1;
#pragma unroll
  for (int r = 0; r < 16; ++r) { am0[r] = 0.f; am1[r] = 0.f; ac0[r] = 0.f; ac1[r] = 0.f; }

#define GISSUE(st_, bs_) {                                                     \
    int tap_ = (st_) >> 4;                                                     \
    int t3_ = tap_ / 3;                                                        \
    int dy_ = t3_ - 1, dx_ = tap_ - 3 * t3_ - 1;                               \
    int dlt_ = dy_ * WF + dx_;                                                 \
    int aoc_ = (((st_) & 15) << 2) + w;   /* CHANNEL octet 0..63 */            \
    char* bp_ = (char*)&lds[bs_][0];                                           \
    _Pragma("unroll") for (int rh_ = 0; rh_ < 2; ++rh_) {                      \
      int iy_ = ya[rh_] + dy_, ix_ = xa[rh_] + dx_;                            \
      bool ok_ = va[rh_] && ((unsigned)iy_ < (unsigned)HF) &&                  \
                 ((unsigned)ix_ < (unsigned)WF);                               \
      size_t ci_ = ((size_t)aoc_ * MTOT +                                      \
                    (size_t)(arw[rh_] + dlt_)) << 3;                           \
      const void* sh_ = ok_ ? (const void*)(inh + ci_) : (const void*)zp;      \
      const void* sl_ = ok_ ? (const void*)(inl + ci_) : (const void*)zp;      \
      gload16(sh_, bp_ + LDS_A_H + w * 2048 + rh_ * 1024);                     \
      gload16(sl_, bp_ + LDS_A_L + w * 2048 + rh_ * 1024);                     \
    }                                                                          \
    {                                                                          \
      size_t bc_ = ((size_t)(4 * (st_) + w) * 512 + (size_t)(n0g + lane)) << 2;\
      gload16(Wph + bc_, bp_ + LDS_B_H + w * 1024);                            \
      gload16(Wpl + bc_, bp_ + LDS_B_L + w * 1024);                            \
    }                                                                          \
  }

#define GCOMPUTE(bs_) {                                                        \
    const char* base_ = (const char*)&lds[bs_][0];                             \
    _Pragma("unroll") for (int h_ = 0; h_ < 2; ++h_) {                         \
      const int oct_ = 2 * h_ + g;                                             \
      const char* pa_ = base_ + LDS_A_H + oct_ * 2048 + (wr * 64 + il) * 16;   \
      const char* qa_ = base_ + LDS_A_L + oct_ * 2048 + (wr * 64 + il) * 16;   \
      const char* pb_ = base_ + LDS_B_H + oct_ * 1024 + (wc * 32 + il) * 16;   \
      const char* qb_ = base_ + LDS_B_L + oct_ * 1024 + (wc * 32 + il) * 16;   \
      f16x8 ah0_ = *(const f16x8*)(pa_);                                       \
      f16x8 ah1_ = *(const f16x8*)(pa_ + 512);                                 \
      f16x8 al0_ = *(const f16x8*)(qa_);                                       \
      f16x8 al1_ = *(const f16x8*)(qa_ + 512);                                 \
      f16x8 bh_ = *(const f16x8*)(pb_);                                        \
      f16x8 bl_ = *(const f16x8*)(qb_);                                        \
      am0 = __builtin_amdgcn_mfma_f32_32x32x16_f16(ah0_, bh_, am0, 0, 0, 0);   \
      am1 = __builtin_amdgcn_mfma_f32_32x32x16_f16(ah1_, bh_, am1, 0, 0, 0);   \
      ac0 = __builtin_amdgcn_mfma_f32_32x32x16_f16(ah0_, bl_, ac0, 0, 0, 0);   \
      ac0 = __builtin_amdgcn_mfma_f32_32x32x16_f16(al0_, bh_, ac0, 0, 0, 0);   \
      ac1 = __builtin_amdgcn_mfma_f32_32x32x16_f16(ah1_, bl_, ac1, 0, 0, 0);   \
      ac1 = __builtin_amdgcn_mfma_f32_32x32x16_f16(al1_, bh_, ac1, 0, 0, 0);   \
    }                                                                          \
  }

  // prologue: fill buffers 0,1; guarantee buf0 landed chip-wide
  GISSUE(0, 0);
  GISSUE(1, 1);
  asm volatile("s_waitcnt vmcnt(6)" ::: "memory");
  __builtin_amdgcn_s_barrier();
  __builtin_amdgcn_sched_barrier(0);

  int cb = 0, ib = 2;
#pragma unroll 1
  for (int st = 0; st < NSTEP; ++st) {
    if (st + 2 < NSTEP) {
      GISSUE(st + 2, ib);
      if (++ib == 3) ib = 0;
    }
    GCOMPUTE(cb);
    __builtin_amdgcn_sched_barrier(0);
    if (st + 2 < NSTEP)
      asm volatile("s_waitcnt vmcnt(6)" ::: "memory");
    else
      asm volatile("s_waitcnt vmcnt(0)" ::: "memory");
    __builtin_amdgcn_s_barrier();
    __builtin_amdgcn_sched_barrier(0);
    if (++cb == 3) cb = 0;
  }
#undef GISSUE
#undef GCOMPUTE

  // C/D 32x32 layout: col = lane&31, row = (r&3)+8*(r>>2)+4*(lane>>5)
  const int colp = n0 + wc * 32 + il;
  const int rb0 = mrow0 + wr * 64 + 4 * g;
#pragma unroll
  for (int r = 0; r < 16; ++r) {
    int row = rb0 + (r & 3) + 8 * (r >> 2);
    if (row < MTOT)
      part0[(size_t)row * ldp + colp] =
          (float)((double)am0[r] + (double)ac0[r] * (1.0 / 4096.0));
    int row2 = row + 32;
    if (row2 < MTOT)
      part0[(size_t)row2 * ldp + colp] =
          (float)((double)am1[r] + (double)ac1[r] * (1.0 / 4096.0));
  }
}

// ---------------- kernel 2: 1x1 heads, 64-pixel tile ----------------
__global__ __launch_bounds__(256) void conv1x1_kernel(
    const float* __restrict__ p0, int ldp, int cbase, int by0,
    const float* __restrict__ convb, const float* __restrict__ W1t,
    float* __restrict__ rawp0, float* __restrict__ rawp1,
    float* __restrict__ rawp2, float* __restrict__ rawp3) {
  __shared__ float As[16][64];
  const int tid = threadIdx.x;
  const int q0 = blockIdx.x * 64;
  const int by = by0 + blockIdx.y;
  const int lane = tid & 63;
  const int wv = tid >> 6;
  const int col0 = __builtin_amdgcn_readfirstlane(wv * 16);
  float* __restrict__ rp = (by == 0) ? rawp0 : (by == 1) ? rawp1 :
                           (by == 2) ? rawp2 : rawp3;

  const int sg = tid >> 6;
  const int sp = tid & 63;
  const int qs = q0 + sp;
  const bool okL = qs < MTOT;

  double acc[16];
  float accf[16];
#pragma unroll
  for (int c = 0; c < 16; ++c) { acc[c] = 0.0; accf[c] = 0.0f; }

  for (int kbl = 0; kbl < 8; ++kbl) {
    int kb = by * 8 + kbl;
    int c0 = kb * 16;                      // global channel
    float fv[4] = {0.0f, 0.0f, 0.0f, 0.0f};
    if (okL) {
      const size_t base = (size_t)qs * ldp + (c0 - cbase) + sg * 4;
      float4 a0 = *(const float4*)&p0[base];
      float4 bsv = *(const float4*)&convb[c0 + sg * 4];
      fv[0] = (float)fmax((double)a0.x + (double)bsv.x, 0.0);
      fv[1] = (float)fmax((double)a0.y + (double)bsv.y, 0.0);
      fv[2] = (float)fmax((double)a0.z + (double)bsv.z, 0.0);
      fv[3] = (float)fmax((double)a0.w + (double)bsv.w, 0.0);
    }
    __syncthreads();
#pragma unroll
    for (int j = 0; j < 4; ++j) As[sg * 4 + j][sp] = fv[j];
    __syncthreads();

    const float* __restrict__ Bw = W1t + (size_t)c0 * 64 + col0;
#pragma unroll
    for (int kk = 0; kk < 16; ++kk) {
      const float* __restrict__ br = Bw + (size_t)kk * 64;
      float a = As[kk][lane];
#pragma unroll
      for (int c = 0; c < 16; ++c)
        accf[c] = fmaf(a, br[c], accf[c]);   // br[c] wave-uniform -> scalar
    }
    if (kbl & 1) {
#pragma unroll
      for (int c = 0; c < 16; ++c) {
        acc[c] += (double)accf[c];
        accf[c] = 0.0f;
      }
    }
  }

  int q = q0 + lane;
  if (q < MTOT) {
    float o[16];
#pragma unroll
    for (int c = 0; c < 16; ++c) o[c] = (float)acc[c];
    float* fp = &rp[(size_t)q * 64 + col0];
#pragma unroll
    for (int g2 = 0; g2 < 4; ++g2)
      *(float4*)&fp[g2 * 4] = make_float4(o[g2*4], o[g2*4+1], o[g2*4+2], o[g2*4+3]);
  }
}

// ---------------- kernel 3: epilogue ----------------
__global__ __launch_bounds__(256) void epilogue_kernel(
    const float* __restrict__ r0, const float* __restrict__ r1,
    const float* __restrict__ r2, const float* __restrict__ r3,
    const float* __restrict__ locb, const float* __restrict__ bfb,
    float* __restrict__ d_out, double* __restrict__ boxd,
    unsigned long long* __restrict__ ukey,
    const int* __restrict__ imh, const int* __restrict__ imw) {
  int idx = blockIdx.x * 256 + threadIdx.x;
  if (idx >= BIMG * NLOC) return;
  int b = idx / NLOC;
  int i = idx - b * NLOC;
  int p = i / ANC;
  int a = i - p * ANC;
  int y = p / WF;
  int x = p - y * WF;
  int q = b * PIX + p;
  const size_t rb = (size_t)q * 64;

  float4 A0 = *(const float4*)&r0[rb + a * 4];
  float4 A1 = *(const float4*)&r1[rb + a * 4];
  float4 A2 = *(const float4*)&r2[rb + a * 4];
  float4 A3 = *(const float4*)&r3[rb + a * 4];
  double l0d = (((double)A0.x + (double)A1.x) + (double)A2.x) + (double)A3.x + (double)locb[a * 4 + 0];
  double l1d = (((double)A0.y + (double)A1.y) + (double)A2.y) + (double)A3.y + (double)locb[a * 4 + 1];
  double l2d = (((double)A0.z + (double)A1.z) + (double)A2.z) + (double)A3.z + (double)locb[a * 4 + 2];
  double l3d = (((double)A0.w + (double)A1.w) + (double)A2.w) + (double)A3.w + (double)locb[a * 4 + 3];
  *(float4*)&d_out[LOC_OFF + (size_t)idx * 4] =
      make_float4((float)l0d, (float)l1d, (float)l2d, (float)l3d);

  float2 G0 = *(const float2*)&r0[rb + 36 + a * 2];
  float2 G1 = *(const float2*)&r1[rb + 36 + a * 2];
  float2 G2 = *(const float2*)&r2[rb + 36 + a * 2];
  float2 G3 = *(const float2*)&r3[rb + 36 + a * 2];
  double g0 = (((double)G0.x + (double)G1.x) + (double)G2.x) + (double)G3.x + (double)bfb[a * 2 + 0];
  double g1 = (((double)G0.y + (double)G1.y) + (double)G2.y) + (double)G3.y + (double)bfb[a * 2 + 1];
  double m  = fmax(g0, g1);
  double e0 = exp(g0 - m), e1 = exp(g1 - m);
  double s  = e0 + e1;
  double p0 = e0 / s, p1 = e1 / s;
  *(float2*)&d_out[BF_OFF + (size_t)idx * 2] = make_float2((float)p0, (float)p1);

  int ridx = a / 3, sidx = a - ridx * 3;
  double ratio = (ridx == 0) ? 0.5 : ((ridx == 1) ? 1.0 : 2.0);
  double scale = (sidx == 0) ? 8.0 : ((sidx == 1) ? 16.0 : 32.0);
  double hs = 16.0 * scale * sqrt(ratio);
  double ws = 16.0 * scale * sqrt(1.0 / ratio);
  double sy = (double)(y * 16), sx = (double)(x * 16);
  double a0 = sy + (8.0 - hs * 0.5);
  double a1 = sx + (8.0 - ws * 0.5);
  double a2 = sy + (8.0 + hs * 0.5);
  double a3 = sx + (8.0 + ws * 0.5);
  if (b == 0) {
    *(float4*)&d_out[ANC_OFF + (size_t)i * 4] =
        make_float4((float)a0, (float)a1, (float)a2, (float)a3);
  }

  double ah = a2 - a0, aw = a3 - a1;
  double acy = a0 + 0.5 * ah, acx = a1 + 0.5 * aw;
  double cy = l0d * ah + acy;
  double cx = l1d * aw + acx;
  double hh = exp(l2d) * ah;
  double ww = exp(l3d) * aw;
  double ihf = (double)imh[0], iwf = (double)imw[0];
  double b0 = fmin(fmax(cy - 0.5 * hh, 0.0), ihf);
  double b1 = fmin(fmax(cx - 0.5 * ww, 0.0), iwf);
  double b2 = fmin(fmax(cy + 0.5 * hh, 0.0), ihf);
  double b3 = fmin(fmax(cx + 0.5 * ww, 0.0), iwf);
  double* bp = &boxd[(size_t)idx * 4];
  bp[0] = b0; bp[1] = b1; bp[2] = b2; bp[3] = b3;

  bool valid = (b2 - b0 >= 16.0) && (b3 - b1 >= 16.0);
  double d = valid ? (g1 - g0) : -INFINITY;
  long long bits = __double_as_longlong(d);
  unsigned long long u = (bits < 0)
      ? ~(unsigned long long)bits
      : ((unsigned long long)bits | 0x8000000000000000ull);
  ukey[idx] = ~u;
}

// ---------------- kernel 4a: histogram threshold + compaction ----------------
__global__ __launch_bounds__(1024) void thresh_kernel(
    const unsigned long long* __restrict__ ukey,
    unsigned* __restrict__ ccnt, unsigned* __restrict__ cand) {
  __shared__ unsigned hist[16384];
  __shared__ unsigned csum[1024];
  __shared__ unsigned sT, scnt;
  int b = blockIdx.x;
  int tid = threadIdx.x;
  for (int i = tid; i < 16384; i += 1024) hist[i] = 0;
  if (tid == 0) scnt = 0;
  __syncthreads();
  for (int j = tid; j < NLOC; j += 1024)
    atomicAdd(&hist[(unsigned)(ukey[(size_t)b * NLOC + j] >> 50)], 1u);
  __syncthreads();
  unsigned s = 0;
#pragma unroll
  for (int k = 0; k < 16; ++k) s += hist[tid * 16 + k];
  csum[tid] = s;
  __syncthreads();
  if (tid == 0) {
    unsigned cum = 0;
    int T = 16383;
    for (int c = 0; c < 1024; ++c) {
      if (cum + csum[c] >= NPRE) {
        unsigned cc = cum;
        for (int k = 0; k < 16; ++k) {
          cc += hist[c * 16 + k];
          if (cc >= NPRE) { T = c * 16 + k; break; }
        }
        break;
      }
      cum += csum[c];
    }
    sT = (unsigned)T;
  }
  __syncthreads();
  unsigned T = sT;
  for (int j = tid; j < NLOC; j += 1024) {
    if ((unsigned)(ukey[(size_t)b * NLOC + j] >> 50) <= T) {
      unsigned slot = atomicAdd(&scnt, 1u);
      if (slot < CAP) cand[(size_t)b * CAP + slot] = (unsigned)j;
    }
  }
  __syncthreads();
  if (tid == 0) ccnt[b] = scnt;
}

// ---------------- kernel 4b: exact rank among candidates -> sb ----------------
__global__ __launch_bounds__(256) void rank_kernel(
    const unsigned long long* __restrict__ ukey, const unsigned* __restrict__ ccnt,
    const unsigned* __restrict__ cand, const double* __restrict__ boxd,
    double* __restrict__ sbd) {
  __shared__ unsigned long long kt[256];
  __shared__ unsigned it[256];
  int b = blockIdx.y;
  int C = (int)min(ccnt[b], (unsigned)CAP);
  int s = blockIdx.x * 256 + threadIdx.x;
  bool act = s < C;
  unsigned myi = act ? cand[(size_t)b * CAP + s] : 0xFFFFFFFFu;
  unsigned long long ki = act ? ukey[(size_t)b * NLOC + myi] : ~0ull;
  int cnt = 0;
  int ntile = (C + 255) >> 8;
  for (int t = 0; t < ntile; ++t) {
    int j = t * 256 + threadIdx.x;
    unsigned ji = (j < C) ? cand[(size_t)b * CAP + j] : 0xFFFFFFFFu;
    kt[threadIdx.x] = (j < C) ? ukey[(size_t)b * NLOC + ji] : ~0ull;
    it[threadIdx.x] = ji;
    __syncthreads();
#pragma unroll 8
    for (int jj = 0; jj < 256; ++jj) {
      unsigned long long kj = kt[jj];
      unsigned jidx = it[jj];
      cnt += ((kj < ki) || (kj == ki && jidx < myi)) ? 1 : 0;
    }
    __syncthreads();
  }
  if (act && cnt < NPRE) {
    const double* bx = &boxd[((size_t)b * NLOC + myi) * 4];
    double* dp = &sbd[((size_t)b * NPRE + cnt) * 4];
    dp[0] = bx[0]; dp[1] = bx[1]; dp[2] = bx[2]; dp[3] = bx[3];
  }
}

// ---------------- kernel 5: NMS bitmask matrix (f64, div-free IoU) ----------------
__global__ __launch_bounds__(64) void nmsmask_kernel(
    const double* __restrict__ sbd, unsigned long long* __restrict__ M) {
  __shared__ double cb[64][4];
  __shared__ double ca[64];
  int b = blockIdx.z;
  int jw = blockIdx.y;
  int i  = blockIdx.x * 64 + threadIdx.x;
  int j  = jw * 64 + threadIdx.x;
  double j0 = 0, j1 = 0, j2 = 0, j3 = 0;
  if (j < NPRE) {
    const double* bp = &sbd[((size_t)b * NPRE + j) * 4];
    j0 = bp[0]; j1 = bp[1]; j2 = bp[2]; j3 = bp[3];
  }
  cb[threadIdx.x][0] = j0; cb[threadIdx.x][1] = j1;
  cb[threadIdx.x][2] = j2; cb[threadIdx.x][3] = j3;
  ca[threadIdx.x] = (j2 - j0) * (j3 - j1) + 1e-9;
  __syncthreads();
  if (i >= NPRE) return;
  const double* bp = &sbd[((size_t)b * NPRE + i) * 4];
  double i0 = bp[0], i1 = bp[1], i2 = bp[2], i3 = bp[3];
  double ai = (i2 - i0) * (i3 - i1);
  unsigned long long mask = 0ull;
#pragma unroll 4
  for (int t = 0; t < 64; ++t) {
    double h = fmax(fmin(i2, cb[t][2]) - fmax(i0, cb[t][0]), 0.0);
    double w = fmax(fmin(i3, cb[t][3]) - fmax(i1, cb[t][1]), 0.0);
    double inter = h * w;
    double rhs = 0.7 * (ai + ca[t] - inter);
    mask |= ((inter > rhs) ? 1ull : 0ull) << t;
  }
  M[((size_t)b * ROWPAD + i) * WSTRIDE + jw] = mask;
}

// ---------------- kernel 6: windowed sequential NMS scan (R8-proven) --------
#define RSTR 49
__global__ __launch_bounds__(64) void nms_scan_kernel(
    const double* __restrict__ sbd, const unsigned long long* __restrict__ M,
    float* __restrict__ d_out) {
  __shared__ unsigned long long rows[64][RSTR];   // 25,088 B
  int b = blockIdx.x;
  int lane = threadIdx.x;
  for (int k = lane; k < NPOST; k += 64) {
    *(float4*)&d_out[ROIS_OFF + (size_t)(b * NPOST + k) * 4] = make_float4(0, 0, 0, 0);
    d_out[IDX_OFF + b * NPOST + k] = (float)b;
  }

  unsigned long long R = ~0ull;
  if (lane < WORDS) R = 0ull;
  for (int w = 0; w < WORDS; ++w) {
    int j = w * 64 + lane;
    bool inval = true;
    if (j < NPRE) {
      const double* bp = &sbd[((size_t)b * NPRE + j) * 4];
      double h = bp[2] - bp[0], wd = bp[3] - bp[1];
      inval = !(h >= 16.0 && wd >= 16.0);
    }
    unsigned long long bal = __ballot(inval ? 1 : 0);
    if (lane == w) R |= bal;
  }

  int kept = 0;
  for (int w0 = 0; w0 < WORDS && kept < NPOST; ++w0) {
    int j = w0 * 64 + lane;
    __syncthreads();                 // previous window's LDS reads done
    if (j < NPRE) {
      const unsigned long long* mr = &M[((size_t)b * ROWPAD + j) * WSTRIDE];
#pragma unroll
      for (int k = 0; k < WORDS; ++k) rows[lane][k] = mr[k];
    }
    __syncthreads();
    unsigned long long word = __shfl(R, w0);   // suppression bits, window w0
    while (kept < NPOST) {
      unsigned long long avail = ~word;
      if (avail == 0ull) break;
      int bit = __ffsll(avail) - 1;
      int i = w0 * 64 + bit;
      if (lane < 4)
        d_out[ROIS_OFF + (size_t)(b * NPOST + kept) * 4 + lane] =
            (float)sbd[((size_t)b * NPRE + i) * 4 + lane];
      kept++;
      if (kept >= NPOST) break;
      unsigned long long rw = (lane < WORDS) ? rows[bit][lane] : 0ull;
      R |= rw;
      word |= (1ull << bit);
      word |= __shfl(rw, w0);
    }
  }
}

// ---------------- launch ----------------
extern "C" void kernel_launch(void* const* d_in, const int* in_sizes, int n_in,
                              void* d_out, int out_size, void* d_ws, size_t ws_size,
                              hipStream_t stream) {
  const float* in     = (const float*)d_in[0];
  const float* conv_w = (const float*)d_in[1];
  const float* conv_b = (const float*)d_in[2];
  const float* bf_w   = (const float*)d_in[3];
  const float* bf_b   = (const float*)d_in[4];
  const float* loc_w  = (const float*)d_in[5];
  const float* loc_b  = (const float*)d_in[6];
  const int*   imh    = (const int*)d_in[7];
  const int*   imw    = (const int*)d_in[8];
  float* out = (float*)d_out;
  char* ws = (char*)d_ws;

  // mode: 1 = gload 1-pass (PROVEN active in R5-R10), 2 = gload 2-pass, 0 = reg
  const int mode = (ws_size >= G1_NEED) ? 1 : (ws_size >= G2_NEED) ? 2 : 0;

  if (mode == 0) {
    unsigned* Wph  = (unsigned*)(ws + WS_WPH);
    unsigned* Wpl  = (unsigned*)(ws + WS_WPL);
    float*    W1t  = (float*)(ws + WS_W1T);
    float*    part0 = (float*)(ws + WS_PART);
    unsigned long long* ukey = (unsigned long long*)(ws + WS_SCORE);
    double*   boxd = (double*)(ws + WS_BOXD);
    double*   sbd  = (double*)(ws + WS_SBD);
    unsigned long long* M = (unsigned long long*)(ws + WS_M);
    unsigned* cand = (unsigned*)(ws + WS_CAND);
    unsigned* ccnt = (unsigned*)(ws + WS_CNT);
    float* rawp0 = (float*)(ws + WS_WPH);
    float* rawp1 = (float*)(ws + WS_WPH + RAWP_SZ);
    float* rawp2 = (float*)(ws + WS_WPH + 2 * RAWP_SZ);
    float* rawp3 = (float*)(ws + WS_RAWP3);

    hipLaunchKernelGGL(prep_kernel, dim3((512 * 256 + 512 * 64 + 255) / 256),
                       dim3(256), 0, stream, conv_w, loc_w, bf_w, Wph, Wpl, W1t);
    hipLaunchKernelGGL(conv3x3_reg, dim3(632), dim3(512), 0, stream,
                       in, (const unsigned*)Wph, (const unsigned*)Wpl, part0);
    hipLaunchKernelGGL(conv1x1_kernel, dim3(157, 4), dim3(256), 0, stream,
                       part0, 512, 0, 0, conv_b, W1t, rawp0, rawp1, rawp2, rawp3);
    hipLaunchKernelGGL(epilogue_kernel, dim3((BIMG * NLOC + 255) / 256), dim3(256),
                       0, stream, rawp0, rawp1, rawp2, rawp3, loc_b, bf_b, out,
                       boxd, ukey, imh, imw);
    hipLaunchKernelGGL(thresh_kernel, dim3(4), dim3(1024), 0, stream, ukey, ccnt, cand);
    hipLaunchKernelGGL(rank_kernel, dim3(CAP / 256, 4), dim3(256), 0, stream,
                       ukey, ccnt, cand, boxd, sbd);
    hipLaunchKernelGGL(nmsmask_kernel, dim3(47, 47, 4), dim3(64), 0, stream, sbd, M);
    hipLaunchKernelGGL(nms_scan_kernel, dim3(4), dim3(64), 0, stream, sbd, M, out);
    return;
  }

  unsigned* Wph = (unsigned*)(ws + G_WPH);
  unsigned* Wpl = (unsigned*)(ws + G_WPL);
  float*    W1t = (float*)(ws + G_W1T);
  unsigned short* inh = (unsigned short*)(ws + G_INH);
  unsigned short* inl = (unsigned short*)(ws + G_INL);
  float* partP = (float*)(ws + G_PART);

  hipLaunchKernelGGL(prep_kernel, dim3((512 * 256 + 512 * 64 + 255) / 256),
                     dim3(256), 0, stream, conv_w, loc_w, bf_w, Wph, Wpl, W1t);
  hipLaunchKernelGGL(packin_kernel, dim3(40, 8, BIMG), dim3(256), 0, stream,
                     in, inh, inl, out);

  float *rawp0, *rawp1, *rawp2, *rawp3;
  unsigned long long *ukey, *M;
  double *boxd, *sbd;
  unsigned *cand, *ccnt;

  if (mode == 1) {
    rawp0 = (float*)(ws + G1_RAWP);
    rawp1 = (float*)(ws + G1_RAWP + RAWP_SZ);
    rawp2 = (float*)(ws + G1_RAWP + 2 * RAWP_SZ);
    rawp3 = (float*)(ws + G1_RAWP + 3 * RAWP_SZ);
    ukey = (unsigned long long*)(ws + G1_UKEY);
    boxd = (double*)(ws + G1_BOXD);
    sbd  = (double*)(ws + G1_SBD);
    M    = (unsigned long long*)(ws + G1_M);
    cand = (unsigned*)(ws + G1_CAND);
    ccnt = (unsigned*)(ws + G1_CNT);

    hipLaunchKernelGGL(conv3x3_g, dim3(632), dim3(256), 0, stream,
                       inh, inl, (const unsigned*)Wph, (const unsigned*)Wpl,
                       partP, (const float*)out, 0, 3, 512);
    hipLaunchKernelGGL(conv1x1_kernel, dim3(157, 4), dim3(256), 0, stream,
                       partP, 512, 0, 0, conv_b, W1t, rawp0, rawp1, rawp2, rawp3);
  } else {
    rawp0 = (float*)(ws + G2_RAWP0);
    rawp1 = (float*)(ws + G2_RAWP1);
    rawp2 = (float*)(ws + G2_RAWP2);
    rawp3 = (float*)(ws + G2_RAWP3);
    ukey = (unsigned long long*)(ws + G2_UKEY);
    boxd = (double*)(ws + G2_BOXD);
    sbd  = (double*)(ws + G2_SBD);
    M    = (unsigned long long*)(ws + G2_M);
    cand = (unsigned*)(ws + G2_CAND);
    ccnt = (unsigned*)(ws + G2_CNT);

    hipLaunchKernelGGL(conv3x3_g, dim3(316), dim3(256), 0, stream,
                       inh, inl, (const unsigned*)Wph, (const unsigned*)Wpl,
                       partP, (const float*)out, 0, 2, 256);
    hipLaunchKernelGGL(conv1x1_kernel, dim3(157, 2), dim3(256), 0, stream,
                       partP, 256, 0, 0, conv_b, W1t, rawp0, rawp1, rawp2, rawp3);
    hipLaunchKernelGGL(conv3x3_g, dim3(316), dim3(256), 0, stream,
                       inh, inl, (const unsigned*)Wph, (const unsigned*)Wpl,
                       partP, (const float*)out, 256, 2, 256);
    hipLaunchKernelGGL(conv1x1_kernel, dim3(157, 2), dim3(256), 0, stream,
                       partP, 256, 256, 2, conv_b, W1t, rawp0, rawp1, rawp2, rawp3);
  }

  hipLaunchKernelGGL(epilogue_kernel, dim3((BIMG * NLOC + 255) / 256), dim3(256),
                     0, stream, rawp0, rawp1, rawp2, rawp3, loc_b, bf_b, out,
                     boxd, ukey, imh, imw);
  hipLaunchKernelGGL(thresh_kernel, dim3(4), dim3(1024), 0, stream, ukey, ccnt, cand);
  hipLaunchKernelGGL(rank_kernel, dim3(CAP / 256, 4), dim3(256), 0, stream,
                     ukey, ccnt, cand, boxd, sbd);
  hipLaunchKernelGGL(nmsmask_kernel, dim3(47, 47, 4), dim3(64), 0, stream, sbd, M);
  hipLaunchKernelGGL(nms_scan_kernel, dim3(4), dim3(64), 0, stream, sbd, M, out);
}